// Round 1
// baseline (23610.814 us; speedup 1.0000x reference)
//
#include <hip/hip_runtime.h>
#include <cstdint>

#define T_STEPS 8192
#define HDIM 1024

__device__ __forceinline__ float dot4(float4 a, float4 b) {
    return a.x * b.x + a.y * b.y + a.z * b.z + a.w * b.w;
}
__device__ __forceinline__ float sigmoidf_(float x) {
    return 1.0f / (1.0f + __expf(-x));
}
__device__ __forceinline__ float tanhf_(float x) {
    return 1.0f - 2.0f / (__expf(2.0f * x) + 1.0f);
}

// 256 blocks x 256 threads, persistent. Wave w of block b owns hidden unit
// u = 4b + w (gate rows u, 1024+u, 2048+u, 3072+u of W_ih / W_hh).
// All weights live in VGPRs (32 float4/thread). Cross-block h handoff is a
// packed (epoch<<32 | f32) 64-bit agent-scope atomic per hidden unit in a
// 2-slot ring in d_ws.
__global__ __launch_bounds__(256, 1)
void lstm_persistent(const float* __restrict__ x,
                     const float* __restrict__ W_ih,
                     const float* __restrict__ W_hh,
                     const float* __restrict__ b_ih,
                     const float* __restrict__ b_hh,
                     const float* __restrict__ h0,
                     const float* __restrict__ c0,
                     float* __restrict__ out,
                     unsigned long long* __restrict__ ring)
{
    __shared__ float h_lds[2][HDIM];

    const int tid = threadIdx.x;
    const int w   = tid >> 6;   // wave 0..3
    const int l   = tid & 63;   // lane
    const int u   = blockIdx.x * 4 + w;

    // ---- register-resident weights: lane l covers elements 4l+256i+j ----
    float4 Whh[4][4], Wih[4][4];
#pragma unroll
    for (int q = 0; q < 4; ++q) {
        const float* rh = W_hh + (size_t)(q * HDIM + u) * HDIM;
        const float* ri = W_ih + (size_t)(q * HDIM + u) * HDIM;
#pragma unroll
        for (int i = 0; i < 4; ++i) {
            Whh[q][i] = *(const float4*)(rh + 4 * l + 256 * i);
            Wih[q][i] = *(const float4*)(ri + 4 * l + 256 * i);
        }
    }
    float bias[4];
#pragma unroll
    for (int q = 0; q < 4; ++q) bias[q] = b_ih[q * HDIM + u] + b_hh[q * HDIM + u];
    float c = c0[u];  // replicated on all lanes of the wave

    float4 hr[4];
#pragma unroll
    for (int i = 0; i < 4; ++i) hr[i] = *(const float4*)(h0 + 4 * l + 256 * i);

    // x prefetch pipeline: xr = x[t+1] (consumed for gx of step t+1), xn = x[t+2]
    float4 xr[4], xn[4];
#pragma unroll
    for (int i = 0; i < 4; ++i) xr[i] = *(const float4*)(x + 4 * l + 256 * i); // x[0]
    float gxp[4];
#pragma unroll
    for (int q = 0; q < 4; ++q) {
        float a = 0.f;
#pragma unroll
        for (int i = 0; i < 4; ++i) a += dot4(Wih[q][i], xr[i]);
        gxp[q] = a;                                    // gx for t = 0
    }
#pragma unroll
    for (int i = 0; i < 4; ++i) xr[i] = *(const float4*)(x + HDIM + 4 * l + 256 * i); // x[1]

    for (int t = 0; t < T_STEPS; ++t) {
        // ---- gate pre-activations: gx (precomputed) + W_hh . h_{t-1} ----
        float acc[4];
#pragma unroll
        for (int q = 0; q < 4; ++q) {
            float a = gxp[q];
#pragma unroll
            for (int i = 0; i < 4; ++i) a += dot4(Whh[q][i], hr[i]);
            acc[q] = a;
        }
        // 64-lane butterfly reduce (all lanes end with the full sum)
#pragma unroll
        for (int m = 1; m < 64; m <<= 1) {
#pragma unroll
            for (int q = 0; q < 4; ++q) acc[q] += __shfl_xor(acc[q], m, 64);
        }
        const float gi = sigmoidf_(acc[0] + bias[0]);
        const float gf = sigmoidf_(acc[1] + bias[1]);
        const float gg = tanhf_   (acc[2] + bias[2]);
        const float go = sigmoidf_(acc[3] + bias[3]);
        c = gf * c + gi * gg;
        const float hval = go * tanhf_(c);

        if (l == 0) {
            out[(size_t)t * HDIM + u] = hval;
            const unsigned long long pk =
                ((unsigned long long)(unsigned)(t + 1) << 32) |
                (unsigned long long)__float_as_uint(hval);
            __hip_atomic_store(&ring[(t & 1) * HDIM + u], pk,
                               __ATOMIC_RELAXED, __HIP_MEMORY_SCOPE_AGENT);
        }
        if (t == T_STEPS - 1) break;

        // issue x[t+2] loads (latency hidden under the spin below)
        {
            const int tn = (t + 2 < T_STEPS) ? (t + 2) : (T_STEPS - 1);
            const float* xp = x + (size_t)tn * HDIM;
#pragma unroll
            for (int i = 0; i < 4; ++i) xn[i] = *(const float4*)(xp + 4 * l + 256 * i);
        }
        // gx partials for step t+1 (independent of h_t -> off the critical path)
#pragma unroll
        for (int q = 0; q < 4; ++q) {
            float a = 0.f;
#pragma unroll
            for (int i = 0; i < 4; ++i) a += dot4(Wih[q][i], xr[i]);
            gxp[q] = a;
        }

        // ---- wait for h_t: one remote round-trip, value rides with epoch ----
        {
            const unsigned e = (unsigned)(t + 1);
            const unsigned long long* rp = ring + (t & 1) * HDIM + tid;
            unsigned long long v0, v1, v2, v3;
            for (;;) {
                v0 = __hip_atomic_load(rp,       __ATOMIC_RELAXED, __HIP_MEMORY_SCOPE_AGENT);
                v1 = __hip_atomic_load(rp + 256, __ATOMIC_RELAXED, __HIP_MEMORY_SCOPE_AGENT);
                v2 = __hip_atomic_load(rp + 512, __ATOMIC_RELAXED, __HIP_MEMORY_SCOPE_AGENT);
                v3 = __hip_atomic_load(rp + 768, __ATOMIC_RELAXED, __HIP_MEMORY_SCOPE_AGENT);
                if ((unsigned)(v0 >> 32) == e && (unsigned)(v1 >> 32) == e &&
                    (unsigned)(v2 >> 32) == e && (unsigned)(v3 >> 32) == e) break;
                __builtin_amdgcn_s_sleep(1);
            }
            const int ns = (t + 1) & 1;
            h_lds[ns][tid      ] = __uint_as_float((unsigned)v0);
            h_lds[ns][tid + 256] = __uint_as_float((unsigned)v1);
            h_lds[ns][tid + 512] = __uint_as_float((unsigned)v2);
            h_lds[ns][tid + 768] = __uint_as_float((unsigned)v3);
        }
        __syncthreads();
        {
            const int ns = (t + 1) & 1;
#pragma unroll
            for (int i = 0; i < 4; ++i)
                hr[i] = *(const float4*)&h_lds[ns][4 * l + 256 * i];
        }
#pragma unroll
        for (int i = 0; i < 4; ++i) xr[i] = xn[i];
    }
}

extern "C" void kernel_launch(void* const* d_in, const int* in_sizes, int n_in,
                              void* d_out, int out_size, void* d_ws, size_t ws_size,
                              hipStream_t stream)
{
    const float* x    = (const float*)d_in[0];
    const float* W_ih = (const float*)d_in[1];
    const float* W_hh = (const float*)d_in[2];
    const float* b_ih = (const float*)d_in[3];
    const float* b_hh = (const float*)d_in[4];
    const float* h0   = (const float*)d_in[5];
    const float* c0   = (const float*)d_in[6];

    unsigned long long* ring = (unsigned long long*)d_ws;
    // zero the epoch ring every call so graph replays are self-consistent
    hipMemsetAsync(d_ws, 0, 2 * HDIM * sizeof(unsigned long long), stream);
    lstm_persistent<<<256, 256, 0, stream>>>(x, W_ih, W_hh, b_ih, b_hh, h0, c0,
                                             (float*)d_out, ring);
}